// Round 9
// baseline (75.215 us; speedup 1.0000x reference)
//
#include <hip/hip_runtime.h>
#include <stdint.h>

// SmoothLoss: total = (1/24) * sum over 24 offsets of mean( exp(-||dx||^2/200) * ||dy||_1 )
// x = rgb2ycbcr(input) (bias cancels in diffs), y = output. 12 offsets, weight 2x.
// R8 = R6 structure (symmetric all-wave gload_lds staging, 2 barriers,
// conflict-free 16B-lane-stride ds_read_b128 Phase C) + half-width tiles:
// COLS=264 -> LDS 38,016B -> 4 blocks/CU (staggered phases fill bubbles).
// Per-half asymmetric staging maps keep gload-written and poison-written LDS
// columns DISJOINT (no ds_write vs gload-retire race):
//   half=0: main gload -> lds[4..259] (img 0..255),   tail(lane0) -> lds[260..263] (img 256..259),  poison cols 0..3
//   half=1: main gload -> lds[0..255] (img 252..507), tail(lane0) -> lds[256..259] (img 508..511),  poison cols 260..263
// Both give: lds col = (img j - jbase) + 4  -> Phase C identical for both halves.
// Poison: plane0=1e19 -> after ycbcr conversion still ~2e17 -> d^2 ~ 5e34 ->
// exp2(-q) == 0 kills OOB terms; no bounds checks in hot loop.
// wgt = exp2f(-q) with K2 = sqrt(0.005/ln2) baked into the ycbcr coefficients.

#define B_ 16
#define H_ 512
#define W_ 512
#define HW_ (H_ * W_)
#define CHW_ (3 * HW_)

#define TH 4          // own rows per block
#define ROWS 6        // TH + 2 bottom halo
#define COLS 264      // 4 | 256 | 4
#define NTHREADS 256
#define POISON 1e19f
#define K2 0.08493218049364766f  // sqrt(0.005 / ln(2))

__global__ void zero_out_kernel(float* p) { p[0] = 0.0f; }

__device__ __forceinline__ void gload16(const float* gsrc, float* ldst) {
  __builtin_amdgcn_global_load_lds(
      (const __attribute__((address_space(1))) void*)gsrc,
      (__attribute__((address_space(3))) void*)ldst, 16, 0, 0);
}

// O[plane][q]: q <-> own img col +q (8 floats)
template <int DW>
__device__ __forceinline__ float contrib0(const float (&O)[6][8]) {
  const float scale = 2.0f / (24.0f * (float)B_ * (float)H_ * (float)(W_ - DW));
  float s = 0.0f;
#pragma unroll
  for (int p = 0; p < 4; ++p) {
    float d0 = O[0][p] - O[0][p + DW];
    float d1 = O[1][p] - O[1][p + DW];
    float d2 = O[2][p] - O[2][p + DW];
    float nq = -(d0 * d0 + d1 * d1 + d2 * d2);
    float wgt = exp2f(nq);
    float l1 = fabsf(O[3][p] - O[3][p + DW]) + fabsf(O[4][p] - O[4][p + DW]) +
               fabsf(O[5][p] - O[5][p + DW]);
    s += wgt * l1;
  }
  return scale * s;
}

// N[plane][q]: q <-> own img col -4+q (12 floats)
template <int DH, int DW>
__device__ __forceinline__ float contribN(const float (&O)[6][8],
                                          const float (&N)[6][12]) {
  constexpr int AW = DW < 0 ? -DW : DW;
  const float scale =
      2.0f / (24.0f * (float)B_ * (float)(H_ - DH) * (float)(W_ - AW));
  float s = 0.0f;
#pragma unroll
  for (int p = 0; p < 4; ++p) {
    const int ni = p + 4 + DW;
    float d0 = O[0][p] - N[0][ni];
    float d1 = O[1][p] - N[1][ni];
    float d2 = O[2][p] - N[2][ni];
    float nq = -(d0 * d0 + d1 * d1 + d2 * d2);
    float wgt = exp2f(nq);
    float l1 = fabsf(O[3][p] - N[3][ni]) + fabsf(O[4][p] - N[4][ni]) +
               fabsf(O[5][p] - N[5][ni]);
    s += wgt * l1;
  }
  return scale * s;
}

__global__ __launch_bounds__(NTHREADS, 4) void smooth_loss_kernel(
    const float* __restrict__ in, const float* __restrict__ outp,
    float* __restrict__ result) {
  __shared__ alignas(16) float lds[6][ROWS][COLS];  // 38,016 B -> 4 blocks/CU
  __shared__ float wsum[4];

  const int tid = threadIdx.x;
  const int wv = tid >> 6;         // 0..3
  const int lane = tid & 63;
  const int by = blockIdx.x;       // 0..127 row tile
  const int half = blockIdx.y;     // 0..1
  const int b = blockIdx.z;        // 0..15
  const int ibase = by * TH;

  const float* inb = in + (size_t)b * CHW_;
  const float* outb = outp + (size_t)b * CHW_;

  // ---- staging: 36 main wave-chunks + 36 single-lane tail chunks ----
#pragma unroll
  for (int k = 0; k < 9; ++k) {
    int idx = wv + 4 * k;          // 0..35, wave-uniform
    int r = idx / 6;
    int p = idx - 6 * r;
    if (ibase + r < H_) {
      const float* rowp =
          (p < 3 ? inb + (size_t)p * HW_ : outb + (size_t)(p - 3) * HW_) +
          (size_t)(ibase + r) * W_;
      if (half == 0)
        gload16(rowp + 4 * lane, &lds[p][r][4]);        // lds 4..259
      else
        gload16(rowp + 252 + 4 * lane, &lds[p][r][0]);  // lds 0..255
    }
  }
  if (lane == 0) {
#pragma unroll
    for (int k = 0; k < 9; ++k) {
      int idx = wv + 4 * k;
      int r = idx / 6;
      int p = idx - 6 * r;
      if (ibase + r < H_) {
        const float* rowp =
            (p < 3 ? inb + (size_t)p * HW_ : outb + (size_t)(p - 3) * HW_) +
            (size_t)(ibase + r) * W_;
        if (half == 0)
          gload16(rowp + 256, &lds[p][r][260]);  // img 256..259
        else
          gload16(rowp + 508, &lds[p][r][256]);  // img 508..511
      }
    }
  }

  // ---- edge-column poison (disjoint from staged columns) ----
  if (tid < 144) {
    int p = tid / 24;
    int rem = tid - 24 * p;
    int r = rem >> 2;
    int ci = rem & 3;
    int col = (half == 0) ? ci : 260 + ci;
    lds[p][r][col] = (p == 0) ? POISON : 0.0f;
  }
  // ---- OOB bottom halo rows (last row-tile only; those rows got no gload) ----
  if (ibase + TH >= H_) {
    for (int c = tid; c < 6 * 2 * COLS; c += NTHREADS) {
      int p = c / (2 * COLS);
      int rem = c - p * (2 * COLS);
      int r = 4 + rem / COLS;
      int col = rem % COLS;
      lds[p][r][col] = (p == 0) ? POISON : 0.0f;
    }
  }

  __syncthreads();  // drains gloads (vmcnt) + poison ds_writes (lgkm)

  // ---- Phase B: in-place rgb -> ycbcr, coefficients x K2 ----
#pragma unroll
  for (int k = 0; k < 2; ++k) {
    int c = tid + NTHREADS * k;    // 396 float4-items = 6 rows x 66
    if (c < ROWS * 66) {
      int r = c / 66;
      int q4 = c - 66 * r;
      int col = 4 * q4;
      float4 rr = *(const float4*)&lds[0][r][col];
      float4 gg = *(const float4*)&lds[1][r][col];
      float4 bb = *(const float4*)&lds[2][r][col];
      float rv[4] = {rr.x, rr.y, rr.z, rr.w};
      float gv[4] = {gg.x, gg.y, gg.z, gg.w};
      float bv[4] = {bb.x, bb.y, bb.z, bb.w};
      float x0[4], x1[4], x2[4];
#pragma unroll
      for (int m = 0; m < 4; ++m) {
        x0[m] = (0.257f * K2) * rv[m] + (0.564f * K2) * gv[m] + (0.098f * K2) * bv[m];
        x1[m] = (-0.148f * K2) * rv[m] + (-0.291f * K2) * gv[m] + (0.439f * K2) * bv[m];
        x2[m] = (0.439f * K2) * rv[m] + (-0.368f * K2) * gv[m] + (-0.071f * K2) * bv[m];
      }
      *(float4*)&lds[0][r][col] = make_float4(x0[0], x0[1], x0[2], x0[3]);
      *(float4*)&lds[1][r][col] = make_float4(x1[0], x1[1], x1[2], x1[3]);
      *(float4*)&lds[2][r][col] = make_float4(x2[0], x2[1], x2[2], x2[3]);
    }
  }

  __syncthreads();

  // ---- Phase C: wave wv owns row wv; lane -> own img cols jbase+4*lane.. ----
  const int jl = 4 * lane;  // lds col of own window start - 4

  float acc = 0.0f;
  float O[6][8];
#pragma unroll
  for (int p6 = 0; p6 < 6; ++p6) {
    *(float4*)&O[p6][0] = *(const float4*)&lds[p6][wv][jl + 4];
    *(float4*)&O[p6][4] = *(const float4*)&lds[p6][wv][jl + 8];
  }

  acc += contrib0<1>(O);
  acc += contrib0<2>(O);

  {
    float N[6][12];
#pragma unroll
    for (int p6 = 0; p6 < 6; ++p6) {
      *(float4*)&N[p6][0] = *(const float4*)&lds[p6][wv + 1][jl];
      *(float4*)&N[p6][4] = *(const float4*)&lds[p6][wv + 1][jl + 4];
      *(float4*)&N[p6][8] = *(const float4*)&lds[p6][wv + 1][jl + 8];
    }
    acc += contribN<1, -2>(O, N);
    acc += contribN<1, -1>(O, N);
    acc += contribN<1, 0>(O, N);
    acc += contribN<1, 1>(O, N);
    acc += contribN<1, 2>(O, N);
  }
  {
    float N[6][12];
#pragma unroll
    for (int p6 = 0; p6 < 6; ++p6) {
      *(float4*)&N[p6][0] = *(const float4*)&lds[p6][wv + 2][jl];
      *(float4*)&N[p6][4] = *(const float4*)&lds[p6][wv + 2][jl + 4];
      *(float4*)&N[p6][8] = *(const float4*)&lds[p6][wv + 2][jl + 8];
    }
    acc += contribN<2, -2>(O, N);
    acc += contribN<2, -1>(O, N);
    acc += contribN<2, 0>(O, N);
    acc += contribN<2, 1>(O, N);
    acc += contribN<2, 2>(O, N);
  }

  // ---- reduction ----
#pragma unroll
  for (int o = 32; o > 0; o >>= 1) acc += __shfl_down(acc, o, 64);
  if (lane == 0) wsum[wv] = acc;
  __syncthreads();
  if (tid == 0) {
    atomicAdd(result, wsum[0] + wsum[1] + wsum[2] + wsum[3]);
  }
}

extern "C" void kernel_launch(void* const* d_in, const int* in_sizes, int n_in,
                              void* d_out, int out_size, void* d_ws, size_t ws_size,
                              hipStream_t stream) {
  const float* in = (const float*)d_in[0];
  const float* outp = (const float*)d_in[1];
  float* res = (float*)d_out;

  zero_out_kernel<<<1, 1, 0, stream>>>(res);

  dim3 grid(H_ / TH, 2, B_);  // (128, 2, 16) = 4096 blocks
  smooth_loss_kernel<<<grid, NTHREADS, 0, stream>>>(in, outp, res);
}

// Round 10
// 60.060 us; speedup vs baseline: 1.2523x; 1.2523x over previous
//
#include <hip/hip_runtime.h>
#include <stdint.h>

// SmoothLoss: total = (1/24) * sum over 24 offsets of mean( exp(-||dx||^2/200) * ||dy||_1 )
// x = rgb2ycbcr(input), y = output; (dh,dw)~(-dh,-dw) pair -> 12 offsets, weight 2x.
// R9: R6 geometry (512 thr, full-width COLS=520, TH=4, 16B-lane-stride b128 windows)
// + double-buffered LDS pipeline: each block owns 8 consecutive row-tiles;
//   stage(tile t+1 -> other buffer) is issued BEFORE compute(tile t), so the
//   barrier's vmcnt(0) drain lands after ~4600cy of compute >> load latency.
//   ONE barrier per tile; only tile0's latency is exposed (once per block).
// + NO ycbcr conversion anywhere: ||M dx||^2 = dx^T (M^T M) dx computed on raw
//   rgb diffs with 6 coeffs pre-negated and pre-scaled by 0.005/ln2 (exp2f).
// Poison: r-plane halo = 1e19 -> nq ~ -2e35 -> exp2 = 0 kills OOB terms (own
// pixel is never poison, so dr is always huge-finite; no inf/nan).

#define B_ 16
#define H_ 512
#define W_ 512
#define HW_ (H_ * W_)
#define CHW_ (3 * HW_)

#define TH 4          // own rows per tile
#define ROWS 6        // TH + 2 bottom halo
#define COLS 520      // 4 | 512 | 4 ; img col j <-> lds col j+4
#define TPB 512
#define NTILES 8      // row-tiles per block
#define POISON 1e19f

__global__ void zero_out_kernel(float* p) { p[0] = 0.0f; }

__device__ __forceinline__ void gload16(const float* gsrc, float* ldst) {
  __builtin_amdgcn_global_load_lds(
      (const __attribute__((address_space(1))) void*)gsrc,
      (__attribute__((address_space(3))) void*)ldst, 16, 0, 0);
}

// nq = -(0.005/ln2) * dx^T (M^T M) dx, computed on raw rgb differences.
constexpr double S_ = 0.005 / 0.69314718055994530942;  // 0.005 / ln(2)
constexpr float CRR = (float)(-S_ * (0.257 * 0.257 + 0.148 * 0.148 + 0.439 * 0.439));
constexpr float CGG = (float)(-S_ * (0.564 * 0.564 + 0.291 * 0.291 + 0.368 * 0.368));
constexpr float CBB = (float)(-S_ * (0.098 * 0.098 + 0.439 * 0.439 + 0.071 * 0.071));
constexpr float CRG = (float)(-2.0 * S_ * (0.257 * 0.564 + (-0.148) * (-0.291) + 0.439 * (-0.368)));
constexpr float CRB = (float)(-2.0 * S_ * (0.257 * 0.098 + (-0.148) * 0.439 + 0.439 * (-0.071)));
constexpr float CGB = (float)(-2.0 * S_ * (0.564 * 0.098 + (-0.291) * 0.439 + (-0.368) * (-0.071)));

__device__ __forceinline__ float wterm(float dr, float dg, float db) {
  float u = CRR * dr + CRG * dg + CRB * db;
  float v = CGG * dg + CGB * db;
  float w = CBB * db;
  float nq = dr * u + dg * v + db * w;   // <= 0 (coeffs negated)
  return exp2f(nq);
}

// planes: 0=r 1=g 2=b 3..5=out. O[p][q]: q <-> own img col +q (8 floats).
template <int DW>
__device__ __forceinline__ float contrib0(const float (&O)[6][8]) {
  const float scale = 2.0f / (24.0f * (float)B_ * (float)H_ * (float)(W_ - DW));
  float s = 0.0f;
#pragma unroll
  for (int p = 0; p < 4; ++p) {
    float wgt = wterm(O[0][p] - O[0][p + DW], O[1][p] - O[1][p + DW],
                      O[2][p] - O[2][p + DW]);
    float l1 = fabsf(O[3][p] - O[3][p + DW]) + fabsf(O[4][p] - O[4][p + DW]) +
               fabsf(O[5][p] - O[5][p + DW]);
    s += wgt * l1;
  }
  return scale * s;
}

// N[p][q]: q <-> own img col -4+q (12 floats)
template <int DH, int DW>
__device__ __forceinline__ float contribN(const float (&O)[6][8],
                                          const float (&N)[6][12]) {
  constexpr int AW = DW < 0 ? -DW : DW;
  const float scale =
      2.0f / (24.0f * (float)B_ * (float)(H_ - DH) * (float)(W_ - AW));
  float s = 0.0f;
#pragma unroll
  for (int p = 0; p < 4; ++p) {
    const int ni = p + 4 + DW;
    float wgt = wterm(O[0][p] - N[0][ni], O[1][p] - N[1][ni],
                      O[2][p] - N[2][ni]);
    float l1 = fabsf(O[3][p] - N[3][ni]) + fabsf(O[4][p] - N[4][ni]) +
               fabsf(O[5][p] - N[5][ni]);
    s += wgt * l1;
  }
  return scale * s;
}

__device__ __forceinline__ void stage_tile(float (*L)[ROWS][COLS], int ibase,
                                           const float* __restrict__ inb,
                                           const float* __restrict__ outb,
                                           int wv, int lane, int tid) {
  // 72 wave-chunks = 6 rows x 6 planes x 2 halves; wave wv takes 9
#pragma unroll
  for (int k = 0; k < 9; ++k) {
    int c = wv + 8 * k;       // wave-uniform
    int r = c / 12;
    int rem = c - 12 * r;
    int p = rem >> 1;
    int h = rem & 1;
    if (ibase + r < H_) {
      const float* src =
          (p < 3 ? inb + (size_t)p * HW_ : outb + (size_t)(p - 3) * HW_) +
          (size_t)(ibase + r) * W_ + 256 * h + 4 * lane;
      gload16(src, &L[p][r][4 + 256 * h]);
    }
  }
  // edge halo columns: r-plane = POISON, others = 0
  if (tid < 288) {
    int p = tid / 48;
    int rem = tid - 48 * p;
    int r = rem >> 3;
    int ci = rem & 7;
    int col = ci < 4 ? ci : 512 + ci;
    L[p][r][col] = (p == 0) ? POISON : 0.0f;
  }
  // bottom OOB halo rows (only the very last tile of the image)
  if (ibase + ROWS - 1 >= H_) {
    for (int c = tid; c < 2 * 6 * 130; c += TPB) {
      int r = 4 + (c >= 780);
      int rem = c % 780;
      int p = rem / 130;
      int q4 = rem - 130 * p;
      float v = (p == 0) ? POISON : 0.0f;
      *(float4*)&L[p][r][4 * q4] = make_float4(v, v, v, v);
    }
  }
}

__global__ __launch_bounds__(TPB, 2) void smooth_loss_kernel(
    const float* __restrict__ in, const float* __restrict__ outp,
    float* __restrict__ result) {
  __shared__ alignas(16) float lds[2][6][ROWS][COLS];  // 149,760 B
  __shared__ float wsum[8];

  const int tid = threadIdx.x;
  const int wv = tid >> 6;       // 0..7
  const int lane = tid & 63;
  const int bx = blockIdx.x;     // 0..15: rows 32*bx .. 32*bx+31
  const int b = blockIdx.y;      // 0..15 batch
  const int base0 = 32 * bx;

  const float* inb = in + (size_t)b * CHW_;
  const float* outb = outp + (size_t)b * CHW_;

  // compute mapping: wave = (half, row); lane -> own img cols j0..j0+3
  const int half = wv >> 2;
  const int row = wv & 3;
  const int jl = 256 * half + 4 * lane;  // lds col of (own img col - 4)

  float acc = 0.0f;

  stage_tile(lds[0], base0, inb, outb, wv, lane, tid);
  __syncthreads();  // only exposed staging latency, once per block

  for (int t = 0; t < NTILES; ++t) {
    if (t < NTILES - 1)
      stage_tile(lds[(t + 1) & 1], base0 + TH * (t + 1), inb, outb, wv, lane, tid);

    float (*L)[ROWS][COLS] = lds[t & 1];

    float O[6][8], N1[6][12], N2[6][12];
#pragma unroll
    for (int p = 0; p < 6; ++p) {
      *(float4*)&O[p][0] = *(const float4*)&L[p][row][jl + 4];
      *(float4*)&O[p][4] = *(const float4*)&L[p][row][jl + 8];
    }
#pragma unroll
    for (int p = 0; p < 6; ++p) {
      *(float4*)&N1[p][0] = *(const float4*)&L[p][row + 1][jl];
      *(float4*)&N1[p][4] = *(const float4*)&L[p][row + 1][jl + 4];
      *(float4*)&N1[p][8] = *(const float4*)&L[p][row + 1][jl + 8];
    }
#pragma unroll
    for (int p = 0; p < 6; ++p) {
      *(float4*)&N2[p][0] = *(const float4*)&L[p][row + 2][jl];
      *(float4*)&N2[p][4] = *(const float4*)&L[p][row + 2][jl + 4];
      *(float4*)&N2[p][8] = *(const float4*)&L[p][row + 2][jl + 8];
    }

    acc += contrib0<1>(O);
    acc += contrib0<2>(O);
    acc += contribN<1, -2>(O, N1);
    acc += contribN<1, -1>(O, N1);
    acc += contribN<1, 0>(O, N1);
    acc += contribN<1, 1>(O, N1);
    acc += contribN<1, 2>(O, N1);
    acc += contribN<2, -2>(O, N2);
    acc += contribN<2, -1>(O, N2);
    acc += contribN<2, 0>(O, N2);
    acc += contribN<2, 1>(O, N2);
    acc += contribN<2, 2>(O, N2);

    __syncthreads();  // drains stage(t+1) gloads (long done) + guards buffer reuse
  }

  // ---- reduction ----
#pragma unroll
  for (int o = 32; o > 0; o >>= 1) acc += __shfl_down(acc, o, 64);
  if (lane == 0) wsum[wv] = acc;
  __syncthreads();
  if (tid == 0) {
    float s = 0.0f;
#pragma unroll
    for (int wq = 0; wq < 8; ++wq) s += wsum[wq];
    atomicAdd(result, s);
  }
}

extern "C" void kernel_launch(void* const* d_in, const int* in_sizes, int n_in,
                              void* d_out, int out_size, void* d_ws, size_t ws_size,
                              hipStream_t stream) {
  const float* in = (const float*)d_in[0];
  const float* outp = (const float*)d_in[1];
  float* res = (float*)d_out;

  zero_out_kernel<<<1, 1, 0, stream>>>(res);

  dim3 grid(H_ / (TH * NTILES), B_, 1);  // (16, 16) = 256 blocks, 1 per CU
  smooth_loss_kernel<<<grid, TPB, 0, stream>>>(in, outp, res);
}

// Round 11
// 54.328 us; speedup vs baseline: 1.3844x; 1.1055x over previous
//
#include <hip/hip_runtime.h>
#include <hip/hip_bf16.h>
#include <stdint.h>

// SmoothLoss: total = (1/24) * sum over 24 offsets of mean( exp(-||dx||^2/200) * ||dy||_1 )
// x = rgb2ycbcr(input) (bias cancels in diffs), y = output. 12 offsets, weight 2x.
// R10 = R6 (champion, 47us) + two micro-deltas only:
//   (1) conversion coefficients pre-scaled by K2 = sqrt(0.005/ln2); contrib uses
//       exp2f(-q) -> v_exp directly (deletes the v_mul from __expf), 12 muls/px.
//   (2) s_setprio(1) around the Phase-C compute cluster (T5): 2 blocks/CU at
//       staggered phases give wave role-diversity for the CU scheduler.
// Structure (R6): 512 thr / 8 waves; TH=4 own rows + 2 halo; full-width COLS=520;
// symmetric all-wave gload_lds staging; poisoned halos (plane0=1e19 -> exp2 -> 0,
// no bounds checks); Phase B in-place ycbcr; Phase C windows as ds_read_b128 at
// 16B lane stride (conflict-free); LDS 74,880B -> 2 blocks/CU.

#define B_ 16
#define H_ 512
#define W_ 512
#define HW_ (H_ * W_)
#define CHW_ (3 * HW_)

#define TH 4          // own rows per block
#define ROWS 6        // TH + 2 bottom halo
#define COLS 520      // 4 pad | 512 | 4 pad ; img col j <-> lds col j+4
#define NTHREADS 512
#define POISON 1e19f
#define K2 0.08493218049364766f  // sqrt(0.005 / ln(2))

__global__ void zero_out_kernel(float* p) { p[0] = 0.0f; }

__device__ __forceinline__ void gload16(const float* gsrc, float* ldst) {
  __builtin_amdgcn_global_load_lds(
      (const __attribute__((address_space(1))) void*)gsrc,
      (__attribute__((address_space(3))) void*)ldst, 16, 0, 0);
}

// O[plane][q]: q <-> img col j0+q (8 floats: own 4 px + 4 right)
template <int DW>
__device__ __forceinline__ float contrib0(const float (&O)[6][8]) {
  const float scale = 2.0f / (24.0f * (float)B_ * (float)H_ * (float)(W_ - DW));
  float s = 0.0f;
#pragma unroll
  for (int p = 0; p < 4; ++p) {
    float d0 = O[0][p] - O[0][p + DW];
    float d1 = O[1][p] - O[1][p + DW];
    float d2 = O[2][p] - O[2][p + DW];
    float nq = -(d0 * d0 + d1 * d1 + d2 * d2);
    float wgt = exp2f(nq);
    float l1 = fabsf(O[3][p] - O[3][p + DW]) + fabsf(O[4][p] - O[4][p + DW]) +
               fabsf(O[5][p] - O[5][p + DW]);
    s += wgt * l1;
  }
  return scale * s;
}

// N[plane][q]: q <-> img col j0-4+q (12 floats)
template <int DH, int DW>
__device__ __forceinline__ float contribN(const float (&O)[6][8],
                                          const float (&N)[6][12]) {
  constexpr int AW = DW < 0 ? -DW : DW;
  const float scale =
      2.0f / (24.0f * (float)B_ * (float)(H_ - DH) * (float)(W_ - AW));
  float s = 0.0f;
#pragma unroll
  for (int p = 0; p < 4; ++p) {
    const int ni = p + 4 + DW;
    float d0 = O[0][p] - N[0][ni];
    float d1 = O[1][p] - N[1][ni];
    float d2 = O[2][p] - N[2][ni];
    float nq = -(d0 * d0 + d1 * d1 + d2 * d2);
    float wgt = exp2f(nq);
    float l1 = fabsf(O[3][p] - N[3][ni]) + fabsf(O[4][p] - N[4][ni]) +
               fabsf(O[5][p] - N[5][ni]);
    s += wgt * l1;
  }
  return scale * s;
}

__global__ __launch_bounds__(NTHREADS, 4) void smooth_loss_kernel(
    const float* __restrict__ in, const float* __restrict__ outp,
    float* __restrict__ result) {
  __shared__ alignas(16) float lds[6][ROWS][COLS];  // 74,880 B
  __shared__ float wsum[8];

  const int tid = threadIdx.x;
  const int wv = tid >> 6;     // 0..7
  const int lane = tid & 63;
  const int by = blockIdx.x;   // 0..127 row tile
  const int b = blockIdx.y;    // 0..15 batch
  const int ibase = by * TH;

  const float* inb = in + (size_t)b * CHW_;
  const float* outb = outp + (size_t)b * CHW_;

  // ---- Phase A: async stage. 72 wave-chunks = 6 rows x 6 planes x 2 halves ----
#pragma unroll
  for (int k = 0; k < 9; ++k) {
    int wc = wv + 8 * k;            // wave-uniform
    int r = wc / 12;
    int rem = wc - 12 * r;
    int p = rem >> 1;
    int h = rem & 1;
    if (ibase + r < H_) {
      const float* src =
          (p < 3 ? inb + (size_t)p * HW_ : outb + (size_t)(p - 3) * HW_) +
          (size_t)(ibase + r) * W_ + 256 * h + 4 * lane;
      gload16(src, &lds[p][r][4 + 256 * h]);
    }
  }

  // ---- poison halo columns (all rows): plane0 = POISON, others = 0 ----
  if (tid < 288) {
    int p = tid / 48;
    int rem = tid - 48 * p;
    int r = rem >> 3;
    int ci = rem & 7;
    int col = ci < 4 ? ci : 512 + ci;
    lds[p][r][col] = (p == 0) ? POISON : 0.0f;
  }
  // ---- poison out-of-range bottom halo rows (only last tile) ----
  if (ibase + TH >= H_) {
    for (int c = tid; c < 6 * 2 * COLS; c += NTHREADS) {
      int p = c / (2 * COLS);
      int rem = c - p * (2 * COLS);
      int r = 4 + rem / COLS;
      int col = rem % COLS;
      lds[p][r][col] = (p == 0) ? POISON : 0.0f;
    }
  }

  __syncthreads();  // drains gload_lds (vmcnt) + ds_writes

  // ---- Phase B: in-place rgb -> ycbcr, coefficients x K2 ----
  {
#pragma unroll
    for (int k = 0; k < 2; ++k) {
      int c = tid + NTHREADS * k;   // 780 float4-items = 6 rows x 130
      if (c < ROWS * 130) {
        int r = c / 130;
        int q4 = c - 130 * r;
        int col = 4 * q4;
        float4 rr = *(const float4*)&lds[0][r][col];
        float4 gg = *(const float4*)&lds[1][r][col];
        float4 bb = *(const float4*)&lds[2][r][col];
        float rv[4] = {rr.x, rr.y, rr.z, rr.w};
        float gv[4] = {gg.x, gg.y, gg.z, gg.w};
        float bv[4] = {bb.x, bb.y, bb.z, bb.w};
        float x0[4], x1[4], x2[4];
#pragma unroll
        for (int m = 0; m < 4; ++m) {
          x0[m] = (0.257f * K2) * rv[m] + (0.564f * K2) * gv[m] + (0.098f * K2) * bv[m];
          x1[m] = (-0.148f * K2) * rv[m] + (-0.291f * K2) * gv[m] + (0.439f * K2) * bv[m];
          x2[m] = (0.439f * K2) * rv[m] + (-0.368f * K2) * gv[m] + (-0.071f * K2) * bv[m];
        }
        *(float4*)&lds[0][r][col] = make_float4(x0[0], x0[1], x0[2], x0[3]);
        *(float4*)&lds[1][r][col] = make_float4(x1[0], x1[1], x1[2], x1[3]);
        *(float4*)&lds[2][r][col] = make_float4(x2[0], x2[1], x2[2], x2[3]);
      }
    }
  }

  __syncthreads();

  // ---- Phase C: wave (half,row); lane handles img cols j0..j0+3 ----
  const int half = wv >> 2;       // 0..1
  const int row = wv & 3;         // own row within tile
  const int j0 = 256 * half + 4 * lane;
  // own img col j <-> lds col j+4; reads at lds cols j0+4, j0+8 (16B lane stride)

  float acc = 0.0f;
  float O[6][8];
#pragma unroll
  for (int p6 = 0; p6 < 6; ++p6) {
    *(float4*)&O[p6][0] = *(const float4*)&lds[p6][row][j0 + 4];
    *(float4*)&O[p6][4] = *(const float4*)&lds[p6][row][j0 + 8];
  }

  __builtin_amdgcn_s_setprio(1);
  acc += contrib0<1>(O);
  acc += contrib0<2>(O);
  __builtin_amdgcn_s_setprio(0);

  {
    float N[6][12];
#pragma unroll
    for (int p6 = 0; p6 < 6; ++p6) {
      *(float4*)&N[p6][0] = *(const float4*)&lds[p6][row + 1][j0];
      *(float4*)&N[p6][4] = *(const float4*)&lds[p6][row + 1][j0 + 4];
      *(float4*)&N[p6][8] = *(const float4*)&lds[p6][row + 1][j0 + 8];
    }
    __builtin_amdgcn_s_setprio(1);
    acc += contribN<1, -2>(O, N);
    acc += contribN<1, -1>(O, N);
    acc += contribN<1, 0>(O, N);
    acc += contribN<1, 1>(O, N);
    acc += contribN<1, 2>(O, N);
    __builtin_amdgcn_s_setprio(0);
  }
  {
    float N[6][12];
#pragma unroll
    for (int p6 = 0; p6 < 6; ++p6) {
      *(float4*)&N[p6][0] = *(const float4*)&lds[p6][row + 2][j0];
      *(float4*)&N[p6][4] = *(const float4*)&lds[p6][row + 2][j0 + 4];
      *(float4*)&N[p6][8] = *(const float4*)&lds[p6][row + 2][j0 + 8];
    }
    __builtin_amdgcn_s_setprio(1);
    acc += contribN<2, -2>(O, N);
    acc += contribN<2, -1>(O, N);
    acc += contribN<2, 0>(O, N);
    acc += contribN<2, 1>(O, N);
    acc += contribN<2, 2>(O, N);
    __builtin_amdgcn_s_setprio(0);
  }

  // ---- reduction ----
#pragma unroll
  for (int o = 32; o > 0; o >>= 1) acc += __shfl_down(acc, o, 64);
  if (lane == 0) wsum[wv] = acc;
  __syncthreads();
  if (tid == 0) {
    float s = 0.0f;
#pragma unroll
    for (int wq = 0; wq < 8; ++wq) s += wsum[wq];
    atomicAdd(result, s);
  }
}

extern "C" void kernel_launch(void* const* d_in, const int* in_sizes, int n_in,
                              void* d_out, int out_size, void* d_ws, size_t ws_size,
                              hipStream_t stream) {
  const float* in = (const float*)d_in[0];
  const float* outp = (const float*)d_in[1];
  float* res = (float*)d_out;

  zero_out_kernel<<<1, 1, 0, stream>>>(res);

  dim3 grid(H_ / TH, B_, 1);  // (128, 16)
  smooth_loss_kernel<<<grid, NTHREADS, 0, stream>>>(in, outp, res);
}

// Round 12
// 49.576 us; speedup vs baseline: 1.5172x; 1.0959x over previous
//
#include <hip/hip_runtime.h>
#include <hip/hip_bf16.h>
#include <stdint.h>

// SmoothLoss: total = (1/24) * sum over 24 offsets of mean( exp(-||dx||^2/200) * ||dy||_1 )
// x = rgb2ycbcr(input) (bias cancels in diffs), y = output. 12 offsets, weight 2x.
// R11 = R10 with ONE fix: exp2f() [OCML libm wrapper, ~8 extra VALU/call] ->
// __builtin_amdgcn_exp2f() [raw v_exp_f32]. K2 = sqrt(0.005/ln2) stays baked
// into the Phase-B ycbcr coefficients, so the weight costs exactly 1 VALU op.
// Structure (R6 champion): 512 thr / 8 waves; TH=4 own rows + 2 halo; COLS=520;
// symmetric all-wave gload_lds staging; poisoned halos (plane0=1e19 -> v_exp
// flushes 2^(-2e35) to +0, no bounds checks); Phase B in-place ycbcr; Phase C
// windows via ds_read_b128 at 16B lane stride (conflict-free); LDS 74,880B ->
// 2 blocks/CU; s_setprio(1) around compute clusters (T5).

#define B_ 16
#define H_ 512
#define W_ 512
#define HW_ (H_ * W_)
#define CHW_ (3 * HW_)

#define TH 4          // own rows per block
#define ROWS 6        // TH + 2 bottom halo
#define COLS 520      // 4 pad | 512 | 4 pad ; img col j <-> lds col j+4
#define NTHREADS 512
#define POISON 1e19f
#define K2 0.08493218049364766f  // sqrt(0.005 / ln(2))

__global__ void zero_out_kernel(float* p) { p[0] = 0.0f; }

__device__ __forceinline__ void gload16(const float* gsrc, float* ldst) {
  __builtin_amdgcn_global_load_lds(
      (const __attribute__((address_space(1))) void*)gsrc,
      (__attribute__((address_space(3))) void*)ldst, 16, 0, 0);
}

// O[plane][q]: q <-> img col j0+q (8 floats: own 4 px + 4 right)
template <int DW>
__device__ __forceinline__ float contrib0(const float (&O)[6][8]) {
  const float scale = 2.0f / (24.0f * (float)B_ * (float)H_ * (float)(W_ - DW));
  float s = 0.0f;
#pragma unroll
  for (int p = 0; p < 4; ++p) {
    float d0 = O[0][p] - O[0][p + DW];
    float d1 = O[1][p] - O[1][p + DW];
    float d2 = O[2][p] - O[2][p + DW];
    float nq = -(d0 * d0 + d1 * d1 + d2 * d2);
    float wgt = __builtin_amdgcn_exp2f(nq);   // raw v_exp_f32
    float l1 = fabsf(O[3][p] - O[3][p + DW]) + fabsf(O[4][p] - O[4][p + DW]) +
               fabsf(O[5][p] - O[5][p + DW]);
    s += wgt * l1;
  }
  return scale * s;
}

// N[plane][q]: q <-> img col j0-4+q (12 floats)
template <int DH, int DW>
__device__ __forceinline__ float contribN(const float (&O)[6][8],
                                          const float (&N)[6][12]) {
  constexpr int AW = DW < 0 ? -DW : DW;
  const float scale =
      2.0f / (24.0f * (float)B_ * (float)(H_ - DH) * (float)(W_ - AW));
  float s = 0.0f;
#pragma unroll
  for (int p = 0; p < 4; ++p) {
    const int ni = p + 4 + DW;
    float d0 = O[0][p] - N[0][ni];
    float d1 = O[1][p] - N[1][ni];
    float d2 = O[2][p] - N[2][ni];
    float nq = -(d0 * d0 + d1 * d1 + d2 * d2);
    float wgt = __builtin_amdgcn_exp2f(nq);   // raw v_exp_f32
    float l1 = fabsf(O[3][p] - N[3][ni]) + fabsf(O[4][p] - N[4][ni]) +
               fabsf(O[5][p] - N[5][ni]);
    s += wgt * l1;
  }
  return scale * s;
}

__global__ __launch_bounds__(NTHREADS, 4) void smooth_loss_kernel(
    const float* __restrict__ in, const float* __restrict__ outp,
    float* __restrict__ result) {
  __shared__ alignas(16) float lds[6][ROWS][COLS];  // 74,880 B
  __shared__ float wsum[8];

  const int tid = threadIdx.x;
  const int wv = tid >> 6;     // 0..7
  const int lane = tid & 63;
  const int by = blockIdx.x;   // 0..127 row tile
  const int b = blockIdx.y;    // 0..15 batch
  const int ibase = by * TH;

  const float* inb = in + (size_t)b * CHW_;
  const float* outb = outp + (size_t)b * CHW_;

  // ---- Phase A: async stage. 72 wave-chunks = 6 rows x 6 planes x 2 halves ----
#pragma unroll
  for (int k = 0; k < 9; ++k) {
    int wc = wv + 8 * k;            // wave-uniform
    int r = wc / 12;
    int rem = wc - 12 * r;
    int p = rem >> 1;
    int h = rem & 1;
    if (ibase + r < H_) {
      const float* src =
          (p < 3 ? inb + (size_t)p * HW_ : outb + (size_t)(p - 3) * HW_) +
          (size_t)(ibase + r) * W_ + 256 * h + 4 * lane;
      gload16(src, &lds[p][r][4 + 256 * h]);
    }
  }

  // ---- poison halo columns (all rows): plane0 = POISON, others = 0 ----
  if (tid < 288) {
    int p = tid / 48;
    int rem = tid - 48 * p;
    int r = rem >> 3;
    int ci = rem & 7;
    int col = ci < 4 ? ci : 512 + ci;
    lds[p][r][col] = (p == 0) ? POISON : 0.0f;
  }
  // ---- poison out-of-range bottom halo rows (only last tile) ----
  if (ibase + TH >= H_) {
    for (int c = tid; c < 6 * 2 * COLS; c += NTHREADS) {
      int p = c / (2 * COLS);
      int rem = c - p * (2 * COLS);
      int r = 4 + rem / COLS;
      int col = rem % COLS;
      lds[p][r][col] = (p == 0) ? POISON : 0.0f;
    }
  }

  __syncthreads();  // drains gload_lds (vmcnt) + ds_writes

  // ---- Phase B: in-place rgb -> ycbcr, coefficients x K2 ----
  {
#pragma unroll
    for (int k = 0; k < 2; ++k) {
      int c = tid + NTHREADS * k;   // 780 float4-items = 6 rows x 130
      if (c < ROWS * 130) {
        int r = c / 130;
        int q4 = c - 130 * r;
        int col = 4 * q4;
        float4 rr = *(const float4*)&lds[0][r][col];
        float4 gg = *(const float4*)&lds[1][r][col];
        float4 bb = *(const float4*)&lds[2][r][col];
        float rv[4] = {rr.x, rr.y, rr.z, rr.w};
        float gv[4] = {gg.x, gg.y, gg.z, gg.w};
        float bv[4] = {bb.x, bb.y, bb.z, bb.w};
        float x0[4], x1[4], x2[4];
#pragma unroll
        for (int m = 0; m < 4; ++m) {
          x0[m] = (0.257f * K2) * rv[m] + (0.564f * K2) * gv[m] + (0.098f * K2) * bv[m];
          x1[m] = (-0.148f * K2) * rv[m] + (-0.291f * K2) * gv[m] + (0.439f * K2) * bv[m];
          x2[m] = (0.439f * K2) * rv[m] + (-0.368f * K2) * gv[m] + (-0.071f * K2) * bv[m];
        }
        *(float4*)&lds[0][r][col] = make_float4(x0[0], x0[1], x0[2], x0[3]);
        *(float4*)&lds[1][r][col] = make_float4(x1[0], x1[1], x1[2], x1[3]);
        *(float4*)&lds[2][r][col] = make_float4(x2[0], x2[1], x2[2], x2[3]);
      }
    }
  }

  __syncthreads();

  // ---- Phase C: wave (half,row); lane handles img cols j0..j0+3 ----
  const int half = wv >> 2;       // 0..1
  const int row = wv & 3;         // own row within tile
  const int j0 = 256 * half + 4 * lane;
  // own img col j <-> lds col j+4; reads at lds cols j0+4, j0+8 (16B lane stride)

  float acc = 0.0f;
  float O[6][8];
#pragma unroll
  for (int p6 = 0; p6 < 6; ++p6) {
    *(float4*)&O[p6][0] = *(const float4*)&lds[p6][row][j0 + 4];
    *(float4*)&O[p6][4] = *(const float4*)&lds[p6][row][j0 + 8];
  }

  __builtin_amdgcn_s_setprio(1);
  acc += contrib0<1>(O);
  acc += contrib0<2>(O);
  __builtin_amdgcn_s_setprio(0);

  {
    float N[6][12];
#pragma unroll
    for (int p6 = 0; p6 < 6; ++p6) {
      *(float4*)&N[p6][0] = *(const float4*)&lds[p6][row + 1][j0];
      *(float4*)&N[p6][4] = *(const float4*)&lds[p6][row + 1][j0 + 4];
      *(float4*)&N[p6][8] = *(const float4*)&lds[p6][row + 1][j0 + 8];
    }
    __builtin_amdgcn_s_setprio(1);
    acc += contribN<1, -2>(O, N);
    acc += contribN<1, -1>(O, N);
    acc += contribN<1, 0>(O, N);
    acc += contribN<1, 1>(O, N);
    acc += contribN<1, 2>(O, N);
    __builtin_amdgcn_s_setprio(0);
  }
  {
    float N[6][12];
#pragma unroll
    for (int p6 = 0; p6 < 6; ++p6) {
      *(float4*)&N[p6][0] = *(const float4*)&lds[p6][row + 2][j0];
      *(float4*)&N[p6][4] = *(const float4*)&lds[p6][row + 2][j0 + 4];
      *(float4*)&N[p6][8] = *(const float4*)&lds[p6][row + 2][j0 + 8];
    }
    __builtin_amdgcn_s_setprio(1);
    acc += contribN<2, -2>(O, N);
    acc += contribN<2, -1>(O, N);
    acc += contribN<2, 0>(O, N);
    acc += contribN<2, 1>(O, N);
    acc += contribN<2, 2>(O, N);
    __builtin_amdgcn_s_setprio(0);
  }

  // ---- reduction ----
#pragma unroll
  for (int o = 32; o > 0; o >>= 1) acc += __shfl_down(acc, o, 64);
  if (lane == 0) wsum[wv] = acc;
  __syncthreads();
  if (tid == 0) {
    float s = 0.0f;
#pragma unroll
    for (int wq = 0; wq < 8; ++wq) s += wsum[wq];
    atomicAdd(result, s);
  }
}

extern "C" void kernel_launch(void* const* d_in, const int* in_sizes, int n_in,
                              void* d_out, int out_size, void* d_ws, size_t ws_size,
                              hipStream_t stream) {
  const float* in = (const float*)d_in[0];
  const float* outp = (const float*)d_in[1];
  float* res = (float*)d_out;

  zero_out_kernel<<<1, 1, 0, stream>>>(res);

  dim3 grid(H_ / TH, B_, 1);  // (128, 16)
  smooth_loss_kernel<<<grid, NTHREADS, 0, stream>>>(in, outp, res);
}